// Round 10
// baseline (261.845 us; speedup 1.0000x reference)
//
#include <hip/hip_runtime.h>

#define THREADS 256
#define BSHIFT 7                    // 128 nodes per bucket
#define BNODES 128
#define CHUNK2 2048                 // edges per fill block (256 threads x 8)
#define CAP 4096                    // slots per bucket (mean 2046 + 45 sigma)

typedef __attribute__((ext_vector_type(8))) short short8;
typedef __attribute__((ext_vector_type(4))) float f32x4;
typedef __attribute__((ext_vector_type(4))) unsigned int u32x4;

__device__ inline unsigned short f2bf(float f) {
  unsigned int u = __float_as_uint(f);
  unsigned int r = u + 0x7fffu + ((u >> 16) & 1u);  // round-to-nearest-even
  return (unsigned short)(r >> 16);
}

// ---------------- binning ----------------

__global__ __launch_bounds__(1024) void init_bcur(int* __restrict__ bcur, int NBK) {
  int t = threadIdx.x;
  if (t < NBK) bcur[t] = t * CAP;
}

// fill path: block-aggregated reservation append of records (dst&127)<<17 | src
__device__ void fill_dev(unsigned char* smem, int bid,
                         const int* __restrict__ src, const int* __restrict__ dst,
                         int* __restrict__ bcur, unsigned* __restrict__ bins,
                         int E, int NBK) {
  int* lcnt  = (int*)smem;
  int* lbase = (int*)(smem + 4096);
  int t = threadIdx.x;
  for (int i = t; i < NBK; i += 256) lcnt[i] = 0;
  __syncthreads();
  int base = bid * CHUNK2;
  unsigned recs[8];
  int bkt[8];
#pragma unroll
  for (int i = 0; i < 8; ++i) {
    int e = base + i * 256 + t;
    if (e < E) {
      int d = dst[e];
      bkt[i] = d >> BSHIFT;
      recs[i] = ((unsigned)(d & (BNODES - 1)) << 17) | (unsigned)src[e];
      atomicAdd(&lcnt[bkt[i]], 1);
    } else bkt[i] = -1;
  }
  __syncthreads();
  for (int i = t; i < NBK; i += 256) {
    int c = lcnt[i];
    lbase[i] = (c > 0) ? atomicAdd(&bcur[i], c) : 0;
  }
  __syncthreads();
  for (int i = t; i < NBK; i += 256) lcnt[i] = 0;
  __syncthreads();
#pragma unroll
  for (int i = 0; i < 8; ++i) {
    if (bkt[i] >= 0) {
      int pos = lbase[bkt[i]] + atomicAdd(&lcnt[bkt[i]], 1);
      if (pos < (bkt[i] + 1) * CAP) bins[pos] = recs[i];  // safety clamp
    }
  }
}

// one block per bucket: two-level (node, src-octant) counting sort.
// adj gets per-node lists grouped by src-octant (2MB feature windows) -> L2 locality.
__global__ __launch_bounds__(256) void bucket_csr(
    const unsigned* __restrict__ bins, const int* __restrict__ bcur,
    int* __restrict__ rowbeg, int* __restrict__ rowend, float* __restrict__ invdeg,
    int* __restrict__ adj, int N) {
  __shared__ int lcnt[1024];
  __shared__ int lrow[1024];
  __shared__ int lcur[1024];
  __shared__ int lpart[256];
  int b = blockIdx.x, t = threadIdx.x;
  for (int i = t; i < 1024; i += 256) { lcnt[i] = 0; lcur[i] = 0; }
  __syncthreads();
  int beg = b * CAP;
  int end = bcur[b];
  if (end > beg + CAP) end = beg + CAP;
  // key = bits 16..14..  (node(7b) << 3) | src_octant(3b) == (v>>14)&1023
  for (int i = beg + t; i < end; i += 256)
    atomicAdd(&lcnt[(bins[i] >> 14) & 1023], 1);
  __syncthreads();
  int c0 = lcnt[4 * t], c1 = lcnt[4 * t + 1], c2 = lcnt[4 * t + 2], c3 = lcnt[4 * t + 3];
  int tot = c0 + c1 + c2 + c3;
  lpart[t] = tot;
  __syncthreads();
  for (int d = 1; d < 256; d <<= 1) {
    int x = (t >= d) ? lpart[t - d] : 0;
    __syncthreads();
    lpart[t] += x;
    __syncthreads();
  }
  int pre = lpart[t] - tot;
  lrow[4 * t]     = beg + pre;
  lrow[4 * t + 1] = beg + pre + c0;
  lrow[4 * t + 2] = beg + pre + c0 + c1;
  lrow[4 * t + 3] = beg + pre + c0 + c1 + c2;
  __syncthreads();
  if (t < BNODES) {
    int g = b * BNODES + t;
    if (g < N) {
      int rb = lrow[t * 8];
      int re = lrow[t * 8 + 7] + lcnt[t * 8 + 7];
      rowbeg[g] = rb;
      rowend[g] = re;
      int dgr = re - rb;
      invdeg[g] = 1.0f / (float)(dgr > 1 ? dgr : 1);
    }
  }
  __syncthreads();
  for (int i = beg + t; i < end; i += 256) {
    unsigned v = bins[i];
    int key = (v >> 14) & 1023;
    int pos = atomicAdd(&lcur[key], 1);
    adj[lrow[key] + pos] = (int)(v & 0x1FFFFu);
  }
}

// ---------------- MFMA GEMM device body ------------------------------------------
// C[N,128] = A[N,128] @ Weff[128,128]^T
// wmode 0 (out-concat): Weff[c][k] = c<64 ? W0[c][k] (W0=[64,128]) : W1[c-64][k]
// wmode 1 (K-concat)  : Weff[c][k] = k<64 ? W0[c][k] (W0=[128,64]) : W1[c][k-64]

__device__ void gemm_dev(unsigned char* Wlds, int bid,
    const void* __restrict__ A0_, const void* __restrict__ A1_, int sa0b, int sa1b, int a_fp32,
    const float* __restrict__ W0, const float* __restrict__ W1, int wmode,
    const float* __restrict__ bias, int relu,
    unsigned short* __restrict__ out0, unsigned short* __restrict__ out1,
    int so0, int so1, int N)
{
  int t = threadIdx.x;
#pragma unroll
  for (int it = 0; it < 8; ++it) {
    int i = it * 256 + t;
    int c = i >> 4, kg = i & 15;
    const float* src;
    if (wmode == 0) src = (c < 64) ? (W0 + c * 128 + kg * 8) : (W1 + (c - 64) * 128 + kg * 8);
    else            src = (kg < 8) ? (W0 + c * 64 + kg * 8)  : (W1 + c * 64 + (kg - 8) * 8);
    short8 v;
#pragma unroll
    for (int q = 0; q < 8; ++q) v[q] = (short)f2bf(src[q]);
    *(short8*)(&Wlds[c * 256 + ((kg * 16) ^ ((c & 7) << 4))]) = v;
  }
  __syncthreads();

  int w = t >> 6, l = t & 63;
  int lr = l & 15, lk = l >> 4;
  int r0 = bid * 128 + w * 32;

  short8 afr[2][4];
#pragma unroll
  for (int set = 0; set < 2; ++set) {
    int row = r0 + set * 16 + lr;
    bool ok = row < N;
    if (a_fp32) {
#pragma unroll
      for (int kt = 0; kt < 4; ++kt) {
        short8 a = {0, 0, 0, 0, 0, 0, 0, 0};
        if (ok) {
          const unsigned char* bp = (const unsigned char*)(kt < 2 ? A0_ : A1_)
                + (size_t)row * (kt < 2 ? sa0b : sa1b) + 32 * lk + 128 * (kt & 1);
          f32x4 f0 = *(const f32x4*)bp;
          f32x4 f1 = *(const f32x4*)(bp + 16);
#pragma unroll
          for (int q = 0; q < 4; ++q) { a[q] = (short)f2bf(f0[q]); a[q + 4] = (short)f2bf(f1[q]); }
        }
        afr[set][kt] = a;
      }
    } else {
#pragma unroll
      for (int kt = 0; kt < 4; ++kt) {
        short8 a = {0, 0, 0, 0, 0, 0, 0, 0};
        if (ok) {
          const unsigned char* bp = (const unsigned char*)(kt < 2 ? A0_ : A1_)
                + (size_t)row * (kt < 2 ? sa0b : sa1b) + 16 * lk + 64 * (kt & 1);
          a = *(const short8*)bp;
        }
        afr[set][kt] = a;
      }
    }
  }

  f32x4 acc[2][8];
#pragma unroll
  for (int s = 0; s < 2; ++s)
#pragma unroll
    for (int c = 0; c < 8; ++c) acc[s][c] = (f32x4){0.f, 0.f, 0.f, 0.f};

#pragma unroll
  for (int ct = 0; ct < 8; ++ct) {
    int c = ct * 16 + lr;
    const unsigned char* rowp = &Wlds[c * 256];
    unsigned swz = (unsigned)((c & 7) << 4);
    short8 bfr[4];
#pragma unroll
    for (int kt = 0; kt < 4; ++kt)
      bfr[kt] = *(const short8*)(rowp + (((unsigned)(16 * lk + 64 * kt)) ^ swz));
#pragma unroll
    for (int kt = 0; kt < 4; ++kt) {
      acc[0][ct] = __builtin_amdgcn_mfma_f32_16x16x32_bf16(afr[0][kt], bfr[kt], acc[0][ct], 0, 0, 0);
      acc[1][ct] = __builtin_amdgcn_mfma_f32_16x16x32_bf16(afr[1][kt], bfr[kt], acc[1][ct], 0, 0, 0);
    }
  }

#pragma unroll
  for (int set = 0; set < 2; ++set) {
    int rbase = r0 + set * 16 + lk * 4;
#pragma unroll
    for (int ct = 0; ct < 8; ++ct) {
      int col = ct * 16 + lr;
      unsigned short* outp = (col < 64) ? out0 : out1;
      int so = (col < 64) ? so0 : so1;
      int cb = (col < 64) ? col : col - 64;
      float bv = bias ? bias[col] : 0.f;
#pragma unroll
      for (int j = 0; j < 4; ++j) {
        int row = rbase + j;
        if (row < N) {
          float v = acc[set][ct][j] + bv;
          if (relu) v = fmaxf(v, 0.f);
          outp[(size_t)row * so + cb] = f2bf(v);
        }
      }
    }
  }
}

__global__ __launch_bounds__(256) void mfma_gemm(
    const void* A0_, const void* A1_, int sa0b, int sa1b, int a_fp32,
    const float* W0, const float* W1, int wmode, const float* bias, int relu,
    unsigned short* out0, unsigned short* out1, int so0, int so1, int N)
{
  __shared__ __align__(16) unsigned char smem[128 * 256];
  gemm_dev(smem, blockIdx.x, A0_, A1_, sa0b, sa1b, a_fp32, W0, W1, wmode,
           bias, relu, out0, out1, so0, so1, N);
}

// merged: blocks [0,gridF) fill bins, blocks [gridF,..) do layer-1 GEMM
__global__ __launch_bounds__(256) void k1_fill_gemm(
    const int* src, const int* dst, int* bcur, unsigned* bins, int E, int NBK, int gridF,
    const void* A0_, const void* A1_, int sa0b, int sa1b,
    const float* W0, const float* W1,
    unsigned short* out0, unsigned short* out1, int so0, int so1, int N)
{
  __shared__ __align__(16) unsigned char smem[128 * 256];
  if (blockIdx.x < gridF)
    fill_dev(smem, blockIdx.x, src, dst, bcur, bins, E, NBK);
  else
    gemm_dev(smem, blockIdx.x - gridF, A0_, A1_, sa0b, sa1b, 1, W0, W1, 0,
             nullptr, 0, out0, out1, so0, so1, N);
}

// ---------------- CSR mean-aggregate, 8 nodes per wave, 16B/lane -------------------

__global__ __launch_bounds__(256) void agg_bf16(
    const unsigned short* __restrict__ feat, const int* __restrict__ adj,
    const int* __restrict__ rowbeg, const int* __restrict__ rowend,
    const float* __restrict__ invdeg,
    const unsigned short* __restrict__ add, const float* __restrict__ bias,
    void* __restrict__ outv, int N, int relu, int out_fp32)
{
  int t = threadIdx.x;
  int lane = t & 63;
  int g8 = lane >> 3, sl = lane & 7;
  int node = blockIdx.x * 32 + (t >> 6) * 8 + g8;
  if (node >= N) return;
  int beg = rowbeg[node], end = rowend[node];
  float s0 = 0.f, s1 = 0.f, s2 = 0.f, s3 = 0.f;
  float s4 = 0.f, s5 = 0.f, s6 = 0.f, s7 = 0.f;
  int j = beg;
  for (; j + 8 <= end; j += 8) {
    u32x4 p[8];
#pragma unroll
    for (int u = 0; u < 8; ++u)
      p[u] = *(const u32x4*)(feat + (size_t)adj[j + u] * 64 + 8 * sl);
#pragma unroll
    for (int u = 0; u < 8; ++u) {
      s0 += __uint_as_float(p[u].x << 16); s1 += __uint_as_float(p[u].x & 0xffff0000u);
      s2 += __uint_as_float(p[u].y << 16); s3 += __uint_as_float(p[u].y & 0xffff0000u);
      s4 += __uint_as_float(p[u].z << 16); s5 += __uint_as_float(p[u].z & 0xffff0000u);
      s6 += __uint_as_float(p[u].w << 16); s7 += __uint_as_float(p[u].w & 0xffff0000u);
    }
  }
  for (; j < end; ++j) {
    u32x4 p = *(const u32x4*)(feat + (size_t)adj[j] * 64 + 8 * sl);
    s0 += __uint_as_float(p.x << 16); s1 += __uint_as_float(p.x & 0xffff0000u);
    s2 += __uint_as_float(p.y << 16); s3 += __uint_as_float(p.y & 0xffff0000u);
    s4 += __uint_as_float(p.z << 16); s5 += __uint_as_float(p.z & 0xffff0000u);
    s6 += __uint_as_float(p.w << 16); s7 += __uint_as_float(p.w & 0xffff0000u);
  }
  float inv = invdeg[node];
  s0 *= inv; s1 *= inv; s2 *= inv; s3 *= inv;
  s4 *= inv; s5 *= inv; s6 *= inv; s7 *= inv;
  if (add) {
    u32x4 q = *(const u32x4*)(add + (size_t)node * 64 + 8 * sl);
    s0 += __uint_as_float(q.x << 16); s1 += __uint_as_float(q.x & 0xffff0000u);
    s2 += __uint_as_float(q.y << 16); s3 += __uint_as_float(q.y & 0xffff0000u);
    s4 += __uint_as_float(q.z << 16); s5 += __uint_as_float(q.z & 0xffff0000u);
    s6 += __uint_as_float(q.w << 16); s7 += __uint_as_float(q.w & 0xffff0000u);
  }
  if (bias) {
    f32x4 b0 = *(const f32x4*)(bias + 8 * sl);
    f32x4 b1 = *(const f32x4*)(bias + 8 * sl + 4);
    s0 += b0[0]; s1 += b0[1]; s2 += b0[2]; s3 += b0[3];
    s4 += b1[0]; s5 += b1[1]; s6 += b1[2]; s7 += b1[3];
  }
  if (relu) {
    s0 = fmaxf(s0, 0.f); s1 = fmaxf(s1, 0.f); s2 = fmaxf(s2, 0.f); s3 = fmaxf(s3, 0.f);
    s4 = fmaxf(s4, 0.f); s5 = fmaxf(s5, 0.f); s6 = fmaxf(s6, 0.f); s7 = fmaxf(s7, 0.f);
  }
  if (out_fp32) {
    float* o = (float*)outv + (size_t)node * 64 + 8 * sl;
    *(f32x4*)o       = (f32x4){s0, s1, s2, s3};
    *(f32x4*)(o + 4) = (f32x4){s4, s5, s6, s7};
  } else {
    u32x4 pk;
    pk.x = ((unsigned)f2bf(s1) << 16) | (unsigned)f2bf(s0);
    pk.y = ((unsigned)f2bf(s3) << 16) | (unsigned)f2bf(s2);
    pk.z = ((unsigned)f2bf(s5) << 16) | (unsigned)f2bf(s4);
    pk.w = ((unsigned)f2bf(s7) << 16) | (unsigned)f2bf(s6);
    *(u32x4*)((unsigned short*)outv + (size_t)node * 64 + 8 * sl) = pk;
  }
}

// ---------------- launch ----------------

extern "C" void kernel_launch(void* const* d_in, const int* in_sizes, int n_in,
                              void* d_out, int out_size, void* d_ws, size_t ws_size,
                              hipStream_t stream) {
  const float* x   = (const float*)d_in[0];
  const int* edges = (const int*)d_in[1];
  const float* Wl1 = (const float*)d_in[2];
  const float* Wr1 = (const float*)d_in[3];
  const float* b1  = (const float*)d_in[4];
  const float* Wl2 = (const float*)d_in[5];
  const float* Wr2 = (const float*)d_in[6];
  const float* b2  = (const float*)d_in[7];
  const float* Wl3 = (const float*)d_in[8];
  const float* Wr3 = (const float*)d_in[9];
  const float* b3  = (const float*)d_in[10];

  int N = in_sizes[0] / 128;
  int E = in_sizes[1] / 2;
  const int* srcp = edges;
  const int* dstp = edges + E;
  int NBK = (N + BNODES - 1) / BNODES;   // 782 buckets for N=100k

  char* ws = (char*)d_ws;
  size_t off = 0;
  auto carve = [&](size_t bytes) -> void* {
    void* p = (void*)(ws + off);
    off += (bytes + 255) & ~(size_t)255;
    return p;
  };
  unsigned* bins = (unsigned*)carve((size_t)NBK * CAP * 4);
  int*   adj    = (int*)carve((size_t)NBK * CAP * 4);
  int*   rowbeg = (int*)carve((size_t)N * 4);
  int*   rowend = (int*)carve((size_t)N * 4);
  int*   bcur   = (int*)carve(1024 * 4);
  float* invdeg = (float*)carve((size_t)N * 4);
  unsigned short* B1 = (unsigned short*)carve((size_t)N * 64 * 2);
  unsigned short* B2 = (unsigned short*)carve((size_t)N * 64 * 2);
  unsigned short* B3 = (unsigned short*)carve((size_t)N * 64 * 2);
  unsigned short* P  = (unsigned short*)carve((size_t)N * 128 * 2);
  (void)ws_size;

  int gridF = (E + CHUNK2 - 1) / CHUNK2;   // 782 fill blocks
  int gridG = (N + 127) / 128;             // 782 gemm blocks
  int gridA = (N + 31) / 32;

  init_bcur<<<1, 1024, 0, stream>>>(bcur, NBK);

  // fill bins  ||  layer-1 GEMM: [z1|y1] = x @ [Wl1|Wr1]^T -> B1(z1), B2(y1)
  k1_fill_gemm<<<gridF + gridG, THREADS, 0, stream>>>(
      srcp, dstp, bcur, bins, E, NBK, gridF,
      x, x + 64, 512, 512, Wl1, Wr1, B1, B2, 64, 64, N);

  bucket_csr<<<NBK, THREADS, 0, stream>>>(bins, bcur, rowbeg, rowend, invdeg, adj, N);

  // h1 = relu(mean(z1) + y1 + b1) -> B3
  agg_bf16<<<gridA, THREADS, 0, stream>>>(B1, adj, rowbeg, rowend, invdeg, B2, b1, B3, N, 1, 0);
  // mean2 = mean(h1) -> B1
  agg_bf16<<<gridA, THREADS, 0, stream>>>(B3, adj, rowbeg, rowend, invdeg, nullptr, nullptr, B1, N, 0, 0);
  // Layer 2 (aggregate-first): h2 = relu([mean2|h1] @ [Wl2,Wr2]_K^T + b2) -> P
  mfma_gemm<<<gridG, THREADS, 0, stream>>>(B1, B3, 128, 128, 0, Wl2, Wr2, 1,
                                           b2, 1, P, P + 64, 128, 128, N);
  // Layer 3 (transform-first): [z3|y3] = h2 @ [Wl3|Wr3]^T -> B2(z3), B1(y3)
  mfma_gemm<<<gridG, THREADS, 0, stream>>>(P, P + 64, 256, 256, 0, Wl3, Wr3, 0,
                                           nullptr, 0, B2, B1, 64, 64, N);
  // out = mean(z3) + y3 + b3 -> d_out (fp32)
  agg_bf16<<<gridA, THREADS, 0, stream>>>(B2, adj, rowbeg, rowend, invdeg, B1, b3, d_out, N, 0, 1);
}

// Round 11
// 215.115 us; speedup vs baseline: 1.2172x; 1.2172x over previous
//
#include <hip/hip_runtime.h>

#define THREADS 256
#define BSHIFT 7                    // 128 nodes per bucket
#define BNODES 128
#define CHUNK 8192                  // edges per binning block
#define BTHREADS 1024
#define CAP 4096                    // slots per bucket (mean 2046 + 45 sigma)

typedef __attribute__((ext_vector_type(8))) short short8;
typedef __attribute__((ext_vector_type(4))) float f32x4;
typedef __attribute__((ext_vector_type(4))) unsigned int u32x4;

__device__ inline unsigned short f2bf(float f) {
  unsigned int u = __float_as_uint(f);
  unsigned int r = u + 0x7fffu + ((u >> 16) & 1u);  // round-to-nearest-even
  return (unsigned short)(r >> 16);
}

// ---------------- binning (capacity-slotted, no count pass) ----------------

__global__ __launch_bounds__(1024) void init_bcur(int* __restrict__ bcur, int NBK) {
  int t = threadIdx.x;
  if (t < NBK) bcur[t] = t * CAP;
}

// records: (dst & 127) << 17 | src   (src < 2^17)
__global__ __launch_bounds__(BTHREADS) void fill_block(
    const int* __restrict__ src, const int* __restrict__ dst,
    int* __restrict__ bcur, unsigned* __restrict__ bins, int E, int NBK) {
  __shared__ int lcnt[1024];
  __shared__ int lbase[1024];
  int t = threadIdx.x;
  lcnt[t] = 0;
  __syncthreads();
  int base = blockIdx.x * CHUNK;
  unsigned recs[CHUNK / BTHREADS];
  int bkt[CHUNK / BTHREADS];
#pragma unroll
  for (int i = 0; i < CHUNK / BTHREADS; ++i) {
    int e = base + i * BTHREADS + t;
    if (e < E) {
      int d = dst[e];
      bkt[i] = d >> BSHIFT;
      recs[i] = ((unsigned)(d & (BNODES - 1)) << 17) | (unsigned)src[e];
      atomicAdd(&lcnt[bkt[i]], 1);
    } else bkt[i] = -1;
  }
  __syncthreads();
  if (t < NBK) {
    int c = lcnt[t];
    lbase[t] = (c > 0) ? atomicAdd(&bcur[t], c) : 0;
  }
  __syncthreads();
  lcnt[t] = 0;
  __syncthreads();
#pragma unroll
  for (int i = 0; i < CHUNK / BTHREADS; ++i) {
    if (bkt[i] >= 0) {
      int pos = lbase[bkt[i]] + atomicAdd(&lcnt[bkt[i]], 1);
      if (pos < (bkt[i] + 1) * CAP) bins[pos] = recs[i];  // safety clamp
    }
  }
}

// one block per bucket: two-level (node, src-octant) counting sort.
// adj gets per-node lists grouped by src-octant (2MB feature windows) -> L2 locality
// for the gather phase: a wave's 8 concurrent lists progress octant-ascending.
__global__ __launch_bounds__(256) void bucket_csr(
    const unsigned* __restrict__ bins, const int* __restrict__ bcur,
    int* __restrict__ rowbeg, int* __restrict__ rowend, float* __restrict__ invdeg,
    int* __restrict__ adj, int N) {
  __shared__ int lcnt[1024];
  __shared__ int lrow[1024];
  __shared__ int lcur[1024];
  __shared__ int lpart[256];
  int b = blockIdx.x, t = threadIdx.x;
  for (int i = t; i < 1024; i += 256) { lcnt[i] = 0; lcur[i] = 0; }
  __syncthreads();
  int beg = b * CAP;
  int end = bcur[b];
  if (end > beg + CAP) end = beg + CAP;
  // key = (node(7b) << 3) | src_octant(3b) == (v>>14)&1023
  for (int i = beg + t; i < end; i += 256)
    atomicAdd(&lcnt[(bins[i] >> 14) & 1023], 1);
  __syncthreads();
  int c0 = lcnt[4 * t], c1 = lcnt[4 * t + 1], c2 = lcnt[4 * t + 2], c3 = lcnt[4 * t + 3];
  int tot = c0 + c1 + c2 + c3;
  lpart[t] = tot;
  __syncthreads();
  for (int d = 1; d < 256; d <<= 1) {
    int x = (t >= d) ? lpart[t - d] : 0;
    __syncthreads();
    lpart[t] += x;
    __syncthreads();
  }
  int pre = lpart[t] - tot;
  lrow[4 * t]     = beg + pre;
  lrow[4 * t + 1] = beg + pre + c0;
  lrow[4 * t + 2] = beg + pre + c0 + c1;
  lrow[4 * t + 3] = beg + pre + c0 + c1 + c2;
  __syncthreads();
  if (t < BNODES) {
    int g = b * BNODES + t;
    if (g < N) {
      int rb = lrow[t * 8];
      int re = lrow[t * 8 + 7] + lcnt[t * 8 + 7];
      rowbeg[g] = rb;
      rowend[g] = re;
      int dgr = re - rb;
      invdeg[g] = 1.0f / (float)(dgr > 1 ? dgr : 1);
    }
  }
  __syncthreads();
  for (int i = beg + t; i < end; i += 256) {
    unsigned v = bins[i];
    int key = (v >> 14) & 1023;
    int pos = atomicAdd(&lcur[key], 1);
    adj[lrow[key] + pos] = (int)(v & 0x1FFFFu);
  }
}

// ---------------- MFMA GEMM: C[N,128] = A[N,128] @ Weff[128,128]^T ------------------
// wmode 0 (out-concat): Weff[c][k] = c<64 ? W0[c][k] (W0=[64,128]) : W1[c-64][k]
// wmode 1 (K-concat)  : Weff[c][k] = k<64 ? W0[c][k] (W0=[128,64]) : W1[c][k-64]

__global__ __launch_bounds__(256) void mfma_gemm(
    const void* __restrict__ A0_, const void* __restrict__ A1_, int sa0b, int sa1b, int a_fp32,
    const float* __restrict__ W0, const float* __restrict__ W1, int wmode,
    const float* __restrict__ bias, int relu,
    unsigned short* __restrict__ out0, unsigned short* __restrict__ out1,
    int so0, int so1, int N)
{
  __shared__ __align__(16) unsigned char Wlds[128 * 256];  // Weff[c][k] bf16, XOR-swizzled
  int t = threadIdx.x;

#pragma unroll
  for (int it = 0; it < 8; ++it) {
    int i = it * 256 + t;
    int c = i >> 4, kg = i & 15;
    const float* src;
    if (wmode == 0) src = (c < 64) ? (W0 + c * 128 + kg * 8) : (W1 + (c - 64) * 128 + kg * 8);
    else            src = (kg < 8) ? (W0 + c * 64 + kg * 8)  : (W1 + c * 64 + (kg - 8) * 8);
    short8 v;
#pragma unroll
    for (int q = 0; q < 8; ++q) v[q] = (short)f2bf(src[q]);
    *(short8*)(&Wlds[c * 256 + ((kg * 16) ^ ((c & 7) << 4))]) = v;
  }
  __syncthreads();

  int w = t >> 6, l = t & 63;
  int lr = l & 15, lk = l >> 4;
  int r0 = blockIdx.x * 128 + w * 32;

  short8 afr[2][4];
#pragma unroll
  for (int set = 0; set < 2; ++set) {
    int row = r0 + set * 16 + lr;
    bool ok = row < N;
    if (a_fp32) {
#pragma unroll
      for (int kt = 0; kt < 4; ++kt) {
        short8 a = {0, 0, 0, 0, 0, 0, 0, 0};
        if (ok) {
          const unsigned char* bp = (const unsigned char*)(kt < 2 ? A0_ : A1_)
                + (size_t)row * (kt < 2 ? sa0b : sa1b) + 32 * lk + 128 * (kt & 1);
          f32x4 f0 = *(const f32x4*)bp;
          f32x4 f1 = *(const f32x4*)(bp + 16);
#pragma unroll
          for (int q = 0; q < 4; ++q) { a[q] = (short)f2bf(f0[q]); a[q + 4] = (short)f2bf(f1[q]); }
        }
        afr[set][kt] = a;
      }
    } else {
#pragma unroll
      for (int kt = 0; kt < 4; ++kt) {
        short8 a = {0, 0, 0, 0, 0, 0, 0, 0};
        if (ok) {
          const unsigned char* bp = (const unsigned char*)(kt < 2 ? A0_ : A1_)
                + (size_t)row * (kt < 2 ? sa0b : sa1b) + 16 * lk + 64 * (kt & 1);
          a = *(const short8*)bp;
        }
        afr[set][kt] = a;
      }
    }
  }

  f32x4 acc[2][8];
#pragma unroll
  for (int s = 0; s < 2; ++s)
#pragma unroll
    for (int c = 0; c < 8; ++c) acc[s][c] = (f32x4){0.f, 0.f, 0.f, 0.f};

#pragma unroll
  for (int ct = 0; ct < 8; ++ct) {
    int c = ct * 16 + lr;
    const unsigned char* rowp = &Wlds[c * 256];
    unsigned swz = (unsigned)((c & 7) << 4);
    short8 bfr[4];
#pragma unroll
    for (int kt = 0; kt < 4; ++kt)
      bfr[kt] = *(const short8*)(rowp + (((unsigned)(16 * lk + 64 * kt)) ^ swz));
#pragma unroll
    for (int kt = 0; kt < 4; ++kt) {
      acc[0][ct] = __builtin_amdgcn_mfma_f32_16x16x32_bf16(afr[0][kt], bfr[kt], acc[0][ct], 0, 0, 0);
      acc[1][ct] = __builtin_amdgcn_mfma_f32_16x16x32_bf16(afr[1][kt], bfr[kt], acc[1][ct], 0, 0, 0);
    }
  }

#pragma unroll
  for (int set = 0; set < 2; ++set) {
    int rbase = r0 + set * 16 + lk * 4;
#pragma unroll
    for (int ct = 0; ct < 8; ++ct) {
      int col = ct * 16 + lr;
      unsigned short* outp = (col < 64) ? out0 : out1;
      int so = (col < 64) ? so0 : so1;
      int cb = (col < 64) ? col : col - 64;
      float bv = bias ? bias[col] : 0.f;
#pragma unroll
      for (int j = 0; j < 4; ++j) {
        int row = rbase + j;
        if (row < N) {
          float v = acc[set][ct][j] + bv;
          if (relu) v = fmaxf(v, 0.f);
          outp[(size_t)row * so + cb] = f2bf(v);
        }
      }
    }
  }
}

// ---------------- CSR mean-aggregate, 8 nodes per wave, 16B/lane -------------------
// 8-lane group per node; lane sl handles channels 8*sl..8*sl+7 (dwordx4 loads).

__global__ __launch_bounds__(256) void agg_bf16(
    const unsigned short* __restrict__ feat, const int* __restrict__ adj,
    const int* __restrict__ rowbeg, const int* __restrict__ rowend,
    const float* __restrict__ invdeg,
    const unsigned short* __restrict__ add, const float* __restrict__ bias,
    void* __restrict__ outv, int N, int relu, int out_fp32)
{
  int t = threadIdx.x;
  int lane = t & 63;
  int g8 = lane >> 3, sl = lane & 7;
  int node = blockIdx.x * 32 + (t >> 6) * 8 + g8;
  if (node >= N) return;
  int beg = rowbeg[node], end = rowend[node];
  float s0 = 0.f, s1 = 0.f, s2 = 0.f, s3 = 0.f;
  float s4 = 0.f, s5 = 0.f, s6 = 0.f, s7 = 0.f;
  int j = beg;
  for (; j + 8 <= end; j += 8) {
    u32x4 p[8];
#pragma unroll
    for (int u = 0; u < 8; ++u)
      p[u] = *(const u32x4*)(feat + (size_t)adj[j + u] * 64 + 8 * sl);
#pragma unroll
    for (int u = 0; u < 8; ++u) {
      s0 += __uint_as_float(p[u].x << 16); s1 += __uint_as_float(p[u].x & 0xffff0000u);
      s2 += __uint_as_float(p[u].y << 16); s3 += __uint_as_float(p[u].y & 0xffff0000u);
      s4 += __uint_as_float(p[u].z << 16); s5 += __uint_as_float(p[u].z & 0xffff0000u);
      s6 += __uint_as_float(p[u].w << 16); s7 += __uint_as_float(p[u].w & 0xffff0000u);
    }
  }
  for (; j < end; ++j) {
    u32x4 p = *(const u32x4*)(feat + (size_t)adj[j] * 64 + 8 * sl);
    s0 += __uint_as_float(p.x << 16); s1 += __uint_as_float(p.x & 0xffff0000u);
    s2 += __uint_as_float(p.y << 16); s3 += __uint_as_float(p.y & 0xffff0000u);
    s4 += __uint_as_float(p.z << 16); s5 += __uint_as_float(p.z & 0xffff0000u);
    s6 += __uint_as_float(p.w << 16); s7 += __uint_as_float(p.w & 0xffff0000u);
  }
  float inv = invdeg[node];
  s0 *= inv; s1 *= inv; s2 *= inv; s3 *= inv;
  s4 *= inv; s5 *= inv; s6 *= inv; s7 *= inv;
  if (add) {
    u32x4 q = *(const u32x4*)(add + (size_t)node * 64 + 8 * sl);
    s0 += __uint_as_float(q.x << 16); s1 += __uint_as_float(q.x & 0xffff0000u);
    s2 += __uint_as_float(q.y << 16); s3 += __uint_as_float(q.y & 0xffff0000u);
    s4 += __uint_as_float(q.z << 16); s5 += __uint_as_float(q.z & 0xffff0000u);
    s6 += __uint_as_float(q.w << 16); s7 += __uint_as_float(q.w & 0xffff0000u);
  }
  if (bias) {
    f32x4 b0 = *(const f32x4*)(bias + 8 * sl);
    f32x4 b1 = *(const f32x4*)(bias + 8 * sl + 4);
    s0 += b0[0]; s1 += b0[1]; s2 += b0[2]; s3 += b0[3];
    s4 += b1[0]; s5 += b1[1]; s6 += b1[2]; s7 += b1[3];
  }
  if (relu) {
    s0 = fmaxf(s0, 0.f); s1 = fmaxf(s1, 0.f); s2 = fmaxf(s2, 0.f); s3 = fmaxf(s3, 0.f);
    s4 = fmaxf(s4, 0.f); s5 = fmaxf(s5, 0.f); s6 = fmaxf(s6, 0.f); s7 = fmaxf(s7, 0.f);
  }
  if (out_fp32) {
    float* o = (float*)outv + (size_t)node * 64 + 8 * sl;
    *(f32x4*)o       = (f32x4){s0, s1, s2, s3};
    *(f32x4*)(o + 4) = (f32x4){s4, s5, s6, s7};
  } else {
    u32x4 pk;
    pk.x = ((unsigned)f2bf(s1) << 16) | (unsigned)f2bf(s0);
    pk.y = ((unsigned)f2bf(s3) << 16) | (unsigned)f2bf(s2);
    pk.z = ((unsigned)f2bf(s5) << 16) | (unsigned)f2bf(s4);
    pk.w = ((unsigned)f2bf(s7) << 16) | (unsigned)f2bf(s6);
    *(u32x4*)((unsigned short*)outv + (size_t)node * 64 + 8 * sl) = pk;
  }
}

// ---------------- launch ----------------

extern "C" void kernel_launch(void* const* d_in, const int* in_sizes, int n_in,
                              void* d_out, int out_size, void* d_ws, size_t ws_size,
                              hipStream_t stream) {
  const float* x   = (const float*)d_in[0];
  const int* edges = (const int*)d_in[1];
  const float* Wl1 = (const float*)d_in[2];
  const float* Wr1 = (const float*)d_in[3];
  const float* b1  = (const float*)d_in[4];
  const float* Wl2 = (const float*)d_in[5];
  const float* Wr2 = (const float*)d_in[6];
  const float* b2  = (const float*)d_in[7];
  const float* Wl3 = (const float*)d_in[8];
  const float* Wr3 = (const float*)d_in[9];
  const float* b3  = (const float*)d_in[10];

  int N = in_sizes[0] / 128;
  int E = in_sizes[1] / 2;
  const int* srcp = edges;
  const int* dstp = edges + E;
  int NBK = (N + BNODES - 1) / BNODES;   // 782 buckets for N=100k

  char* ws = (char*)d_ws;
  size_t off = 0;
  auto carve = [&](size_t bytes) -> void* {
    void* p = (void*)(ws + off);
    off += (bytes + 255) & ~(size_t)255;
    return p;
  };
  unsigned* bins = (unsigned*)carve((size_t)NBK * CAP * 4);
  int*   adj    = (int*)carve((size_t)NBK * CAP * 4);
  int*   rowbeg = (int*)carve((size_t)N * 4);
  int*   rowend = (int*)carve((size_t)N * 4);
  int*   bcur   = (int*)carve(1024 * 4);
  float* invdeg = (float*)carve((size_t)N * 4);
  unsigned short* B1 = (unsigned short*)carve((size_t)N * 64 * 2);
  unsigned short* B2 = (unsigned short*)carve((size_t)N * 64 * 2);
  unsigned short* B3 = (unsigned short*)carve((size_t)N * 64 * 2);
  unsigned short* P  = (unsigned short*)carve((size_t)N * 128 * 2);
  (void)ws_size;

  int gridF = (E + CHUNK - 1) / CHUNK;   // 196 blocks
  int gridG = (N + 127) / 128;
  int gridA = (N + 31) / 32;

  init_bcur<<<1, 1024, 0, stream>>>(bcur, NBK);
  fill_block<<<gridF, BTHREADS, 0, stream>>>(srcp, dstp, bcur, bins, E, NBK);
  bucket_csr<<<NBK, THREADS, 0, stream>>>(bins, bcur, rowbeg, rowend, invdeg, adj, N);

  // Layer 1 (transform-first): [z1|y1] = x @ [Wl1|Wr1]^T -> B1(z1), B2(y1)   [A fp32]
  mfma_gemm<<<gridG, THREADS, 0, stream>>>(x, x + 64, 512, 512, 1, Wl1, Wr1, 0,
                                           nullptr, 0, B1, B2, 64, 64, N);
  // h1 = relu(mean(z1) + y1 + b1) -> B3
  agg_bf16<<<gridA, THREADS, 0, stream>>>(B1, adj, rowbeg, rowend, invdeg, B2, b1, B3, N, 1, 0);
  // mean2 = mean(h1) -> B1
  agg_bf16<<<gridA, THREADS, 0, stream>>>(B3, adj, rowbeg, rowend, invdeg, nullptr, nullptr, B1, N, 0, 0);
  // Layer 2 (aggregate-first): h2 = relu([mean2|h1] @ [Wl2,Wr2]_K^T + b2) -> P
  mfma_gemm<<<gridG, THREADS, 0, stream>>>(B1, B3, 128, 128, 0, Wl2, Wr2, 1,
                                           b2, 1, P, P + 64, 128, 128, N);
  // Layer 3 (transform-first): [z3|y3] = h2 @ [Wl3|Wr3]^T -> B2(z3), B1(y3)
  mfma_gemm<<<gridG, THREADS, 0, stream>>>(P, P + 64, 256, 256, 0, Wl3, Wr3, 0,
                                           nullptr, 0, B2, B1, 64, 64, N);
  // out = mean(z3) + y3 + b3 -> d_out (fp32)
  agg_bf16<<<gridA, THREADS, 0, stream>>>(B2, adj, rowbeg, rowend, invdeg, B1, b3, d_out, N, 0, 1);
}